// Round 1
// baseline (624.870 us; speedup 1.0000x reference)
//
#include <hip/hip_runtime.h>
#include <hip/hip_bf16.h>

#define B_N    64
#define K_LEN  2000
#define D_DIM  512
#define NEG_INF (-3.402823466e38f)
#define EPS_C  1e-6f
#define INV_SCALE (1.0f/22.62741699796952f)   // 1/sqrt(512)

// ---------------- kernel 1a: q projections (mono & chunk) ----------------
// q[b,br,a] = sum_d query[b,d] * Wq[d,a] + bq[a]
__global__ __launch_bounds__(256) void qproj_kernel(
    const float* __restrict__ query,
    const float* __restrict__ Wq_m, const float* __restrict__ bq_m,
    const float* __restrict__ Wq_c, const float* __restrict__ bq_c,
    float* __restrict__ q_all)
{
    const int b = blockIdx.x, br = blockIdx.y;
    const float* W = br ? Wq_c : Wq_m;
    const float* bias = br ? bq_c : bq_m;
    __shared__ float qs[D_DIM];
    for (int i = threadIdx.x; i < D_DIM; i += 256) qs[i] = query[(size_t)b*D_DIM + i];
    __syncthreads();
    for (int a = threadIdx.x; a < D_DIM; a += 256) {
        float acc = bias[a];
        for (int d = 0; d < D_DIM; ++d) acc = fmaf(qs[d], W[(size_t)d*D_DIM + a], acc);
        q_all[((size_t)b*2 + br)*D_DIM + a] = acc;
    }
}

// ---------------- kernel 1b: fold Wk into per-batch vector ----------------
// v[b,br,d] = (sum_a Wk[d,a]*q[b,br,a]) / scale ;  c[b,br] = q·bk/scale (+r)
__global__ __launch_bounds__(256) void vproj_kernel(
    const float* __restrict__ q_all,
    const float* __restrict__ Wk_m, const float* __restrict__ bk_m,
    const float* __restrict__ Wk_c, const float* __restrict__ bk_c,
    const float* __restrict__ r,
    float* __restrict__ v_all, float* __restrict__ c_all)
{
    const int b = blockIdx.x, br = blockIdx.y, t = threadIdx.x;
    const float* W = br ? Wk_c : Wk_m;
    const float* bias = br ? bk_c : bk_m;
    __shared__ float qs[D_DIM];
    __shared__ float red[256];
    for (int i = t; i < D_DIM; i += 256) qs[i] = q_all[((size_t)b*2 + br)*D_DIM + i];
    __syncthreads();
    for (int d = t; d < D_DIM; d += 256) {
        const float4* row = (const float4*)(W + (size_t)d*D_DIM);
        const float4* q4 = (const float4*)qs;
        float acc = 0.f;
        #pragma unroll 4
        for (int a4 = 0; a4 < D_DIM/4; ++a4) {
            float4 w = row[a4], q = q4[a4];
            acc = fmaf(w.x, q.x, acc); acc = fmaf(w.y, q.y, acc);
            acc = fmaf(w.z, q.z, acc); acc = fmaf(w.w, q.w, acc);
        }
        v_all[((size_t)b*2 + br)*D_DIM + d] = acc * INV_SCALE;
    }
    float part = 0.f;
    for (int a = t; a < D_DIM; a += 256) part = fmaf(qs[a], bias[a], part);
    red[t] = part; __syncthreads();
    for (int s = 128; s; s >>= 1) { if (t < s) red[t] += red[t + s]; __syncthreads(); }
    if (t == 0) c_all[b*2 + br] = red[0] * INV_SCALE + (br ? 0.f : r[0]);
}

// ---------------- kernel 2: energies (one pass over key) ----------------
// e_mono[b,k] = key[b,k]·v_mono[b] + c_mono[b]   (masked -> NEG_INF)
// e_c   [b,k] = key[b,k]·v_chunk[b] + c_chunk[b] (masked -> NEG_INF)
__global__ __launch_bounds__(256) void energy_kernel(
    const float* __restrict__ key, const int* __restrict__ mask,
    const float* __restrict__ v_all, const float* __restrict__ c_all,
    float* __restrict__ e_mono, float* __restrict__ e_c)
{
    const int b = blockIdx.x;
    const int kb0 = blockIdx.y * 125;          // 16 chunks * 125 = 2000
    const int kend = kb0 + 125;
    const int lane = threadIdx.x & 63;
    const int wave = threadIdx.x >> 6;
    const float4* vm4 = (const float4*)(v_all + ((size_t)b*2 + 0)*D_DIM);
    const float4* vc4 = (const float4*)(v_all + ((size_t)b*2 + 1)*D_DIM);
    const float4 vmA = vm4[lane*2], vmB = vm4[lane*2 + 1];
    const float4 vcA = vc4[lane*2], vcB = vc4[lane*2 + 1];
    const float cm = c_all[b*2 + 0], cc = c_all[b*2 + 1];

    for (int k = kb0 + wave; k < kend; k += 4) {
        const float4* kr = (const float4*)(key + ((size_t)b*K_LEN + k)*D_DIM);
        float4 ka = kr[lane*2], kb4 = kr[lane*2 + 1];
        float dm = 0.f, dc = 0.f;
        dm = fmaf(ka.x, vmA.x, dm); dm = fmaf(ka.y, vmA.y, dm);
        dm = fmaf(ka.z, vmA.z, dm); dm = fmaf(ka.w, vmA.w, dm);
        dm = fmaf(kb4.x, vmB.x, dm); dm = fmaf(kb4.y, vmB.y, dm);
        dm = fmaf(kb4.z, vmB.z, dm); dm = fmaf(kb4.w, vmB.w, dm);
        dc = fmaf(ka.x, vcA.x, dc); dc = fmaf(ka.y, vcA.y, dc);
        dc = fmaf(ka.z, vcA.z, dc); dc = fmaf(ka.w, vcA.w, dc);
        dc = fmaf(kb4.x, vcB.x, dc); dc = fmaf(kb4.y, vcB.y, dc);
        dc = fmaf(kb4.z, vcB.z, dc); dc = fmaf(kb4.w, vcB.w, dc);
        #pragma unroll
        for (int off = 32; off; off >>= 1) {
            dm += __shfl_xor(dm, off);
            dc += __shfl_xor(dc, off);
        }
        if (lane == 0) {
            const size_t gk = (size_t)b*K_LEN + k;
            const bool mk = mask[gk] != 0;
            e_mono[gk] = mk ? dm + cm : NEG_INF;
            e_c[gk]    = mk ? dc + cc : NEG_INF;
        }
    }
}

// ---------------- kernel 3: per-batch scans -> alpha, beta ----------------
__global__ __launch_bounds__(256) void scan_kernel(
    const float* __restrict__ e_mono_g, const float* __restrict__ e_c_g,
    const float* __restrict__ noise, const float* __restrict__ aw_prev,
    float* __restrict__ alpha_out, float* __restrict__ beta_out)
{
    const int b = blockIdx.x, t = threadIdx.x;
    __shared__ float sp[2048];   // p
    __shared__ float scp[2048];  // log(1-p) then cumprod
    __shared__ float sal[2048];  // alpha
    __shared__ float sse[2048];  // e_c then sm_exp
    __shared__ float su[2048];   // alpha/denom
    __shared__ float scan[256];

    const float* em = e_mono_g + (size_t)b*K_LEN;
    const float* ec = e_c_g   + (size_t)b*K_LEN;
    const float* nz = noise   + (size_t)b*K_LEN;
    const float* aw = aw_prev + (size_t)b*K_LEN;

    for (int k = t; k < 2048; k += 256) {
        float p = 0.f, lg = 0.f, ecv = NEG_INF;
        if (k < K_LEN) {
            float e = em[k] + nz[k];             // NOISE_STD = 1
            p = 1.f / (1.f + expf(-e));
            float om = fminf(fmaxf(1.f - p, EPS_C), 1.f);
            lg = logf(om);
            ecv = ec[k];
        }
        sp[k] = p; scp[k] = lg; sse[k] = ecv;
    }
    __syncthreads();

    // exclusive cumsum of log(1-p) -> cumprod_1mp
    const int base = t*8;
    float ex[8]; float run = 0.f;
    #pragma unroll
    for (int j = 0; j < 8; ++j) { ex[j] = run; run += scp[base + j]; }
    scan[t] = run; __syncthreads();
    for (int off = 1; off < 256; off <<= 1) {
        float x = (t >= off) ? scan[t - off] : 0.f; __syncthreads();
        scan[t] += x; __syncthreads();
    }
    const float pre = scan[t] - run;

    float t2i[8]; float run2 = 0.f;
    #pragma unroll
    for (int j = 0; j < 8; ++j) {
        int k = base + j;
        float cp = expf(pre + ex[j]);
        scp[k] = cp;
        float t2 = 0.f;
        if (k < K_LEN) t2 = aw[k] / fminf(fmaxf(cp, EPS_C), 1.f);
        run2 += t2; t2i[j] = run2;               // inclusive within thread
    }
    __syncthreads();
    scan[t] = run2; __syncthreads();
    for (int off = 1; off < 256; off <<= 1) {
        float x = (t >= off) ? scan[t - off] : 0.f; __syncthreads();
        scan[t] += x; __syncthreads();
    }
    const float pre2 = scan[t] - run2;
    #pragma unroll
    for (int j = 0; j < 8; ++j) {
        int k = base + j;
        float al = sp[k] * scp[k] * (pre2 + t2i[j]);
        sal[k] = al;
        if (k < K_LEN) alpha_out[(size_t)b*K_LEN + k] = al;
    }

    // max over e_c
    float mx = NEG_INF;
    for (int k = t; k < 2048; k += 256) mx = fmaxf(mx, sse[k]);
    __syncthreads();
    scan[t] = mx; __syncthreads();
    for (int s = 128; s; s >>= 1) { if (t < s) scan[t] = fmaxf(scan[t], scan[t + s]); __syncthreads(); }
    mx = scan[0];

    for (int k = t; k < 2048; k += 256) {
        float se = 0.f;
        if (k < K_LEN) se = fmaxf(expf(sse[k] - mx), 1e-5f);
        sse[k] = se;
    }
    __syncthreads();
    // denom = moving_sum(sm_exp, back=7, fwd=0); u = alpha/denom
    for (int k = t; k < 2048; k += 256) {
        float u = 0.f;
        if (k < K_LEN) {
            float den = 0.f;
            int j0 = (k > 7) ? (k - 7) : 0;
            for (int j = j0; j <= k; ++j) den += sse[j];
            u = sal[k] / den;                    // SHARP = 1
        }
        su[k] = u;
    }
    __syncthreads();
    // beta = sm_exp * moving_sum(u, back=0, fwd=7)
    for (int k = t; k < K_LEN; k += 256) {
        float s2 = 0.f;
        #pragma unroll
        for (int j = 0; j < 8; ++j) s2 += su[k + j];
        beta_out[(size_t)b*K_LEN + k] = sse[k] * s2;
    }
}

// ---------------- kernel 4: cv partials (one pass over value) ----------------
__global__ __launch_bounds__(128) void cv_part_kernel(
    const float* __restrict__ value, const float* __restrict__ beta,
    float* __restrict__ partial)   // [B][40][512]
{
    const int b = blockIdx.x, s = blockIdx.y, t = threadIdx.x;
    const int k0 = s * 50, k1 = k0 + 50;
    __shared__ float bs[50];
    if (t < 50) bs[t] = beta[(size_t)b*K_LEN + k0 + t];
    __syncthreads();
    float4 acc = {0.f, 0.f, 0.f, 0.f};
    for (int k = k0; k < k1; ++k) {
        float4 vv = ((const float4*)(value + ((size_t)b*K_LEN + k)*D_DIM))[t];
        float bb = bs[k - k0];
        acc.x = fmaf(bb, vv.x, acc.x); acc.y = fmaf(bb, vv.y, acc.y);
        acc.z = fmaf(bb, vv.z, acc.z); acc.w = fmaf(bb, vv.w, acc.w);
    }
    ((float4*)(partial + ((size_t)b*40 + s)*D_DIM))[t] = acc;
}

__global__ __launch_bounds__(256) void cv_reduce_kernel(
    const float* __restrict__ partial, float* __restrict__ cv)
{
    const int idx = blockIdx.x*256 + threadIdx.x;     // 0..32767
    const int b = idx >> 9, d = idx & 511;
    float acc = 0.f;
    for (int s = 0; s < 40; ++s) acc += partial[((size_t)b*40 + s)*D_DIM + d];
    cv[idx] = acc;
}

extern "C" void kernel_launch(void* const* d_in, const int* in_sizes, int n_in,
                              void* d_out, int out_size, void* d_ws, size_t ws_size,
                              hipStream_t stream) {
    const float* key     = (const float*)d_in[0];
    const float* value   = (const float*)d_in[1];
    const float* query   = (const float*)d_in[2];
    const int*   mask    = (const int*)d_in[3];
    const float* aw_prev = (const float*)d_in[4];
    const float* noise   = (const float*)d_in[5];
    const float* Wk_m    = (const float*)d_in[6];
    const float* bk_m    = (const float*)d_in[7];
    const float* Wq_m    = (const float*)d_in[8];
    const float* bq_m    = (const float*)d_in[9];
    const float* r       = (const float*)d_in[10];
    const float* Wk_c    = (const float*)d_in[11];
    const float* bk_c    = (const float*)d_in[12];
    const float* Wq_c    = (const float*)d_in[13];
    const float* bq_c    = (const float*)d_in[14];

    float* out   = (float*)d_out;
    float* cv    = out;                       // [64,1,512] = 32768
    float* alpha = out + (size_t)B_N*D_DIM;   // [64,2000]  = 128000

    float* ws      = (float*)d_ws;
    float* e_mono  = ws;                  // 128000
    float* e_c     = ws + 128000;         // 128000
    float* beta    = ws + 256000;         // 128000
    float* q_all   = ws + 384000;         // 65536
    float* v_all   = ws + 449536;         // 65536
    float* c_all   = ws + 515072;         // 128
    float* partial = ws + 515200;         // 64*40*512 = 1310720

    qproj_kernel<<<dim3(B_N, 2), 256, 0, stream>>>(query, Wq_m, bq_m, Wq_c, bq_c, q_all);
    vproj_kernel<<<dim3(B_N, 2), 256, 0, stream>>>(q_all, Wk_m, bk_m, Wk_c, bk_c, r, v_all, c_all);
    energy_kernel<<<dim3(B_N, 16), 256, 0, stream>>>(key, mask, v_all, c_all, e_mono, e_c);
    scan_kernel<<<B_N, 256, 0, stream>>>(e_mono, e_c, noise, aw_prev, alpha, beta);
    cv_part_kernel<<<dim3(B_N, 40), 128, 0, stream>>>(value, beta, partial);
    cv_reduce_kernel<<<32768/256, 256, 0, stream>>>(partial, cv);
}

// Round 2
// 613.178 us; speedup vs baseline: 1.0191x; 1.0191x over previous
//
#include <hip/hip_runtime.h>
#include <hip/hip_bf16.h>

#define B_N    64
#define K_LEN  2000
#define D_DIM  512
#define NEG_INF (-3.402823466e38f)
#define EPS_C  1e-6f
#define INV_SCALE (1.0f/22.62741699796952f)   // 1/sqrt(512)

// -------- kernel 1: fused q/v projection per (b,branch) --------
// stage1: q[a] = query[b]·Wq[:,a] + bq[a]
// stage2: v[d] = (Wk[d,:]·q)/scale ; c = (q·bk)/scale (+ r for mono)
__global__ __launch_bounds__(256) void proj_kernel(
    const float* __restrict__ query,
    const float* __restrict__ Wq_m, const float* __restrict__ bq_m,
    const float* __restrict__ Wq_c, const float* __restrict__ bq_c,
    const float* __restrict__ Wk_m, const float* __restrict__ bk_m,
    const float* __restrict__ Wk_c, const float* __restrict__ bk_c,
    const float* __restrict__ r,
    float* __restrict__ v_all, float* __restrict__ c_all)
{
    const int b = blockIdx.x, br = blockIdx.y, t = threadIdx.x;
    const float* Wq = br ? Wq_c : Wq_m;
    const float* bq = br ? bq_c : bq_m;
    const float* Wk = br ? Wk_c : Wk_m;
    const float* bk = br ? bk_c : bk_m;
    __shared__ float qs[D_DIM];   // query vector
    __shared__ float qv[D_DIM];   // projected q
    __shared__ float red[256];
    for (int i = t; i < D_DIM; i += 256) qs[i] = query[(size_t)b*D_DIM + i];
    __syncthreads();
    // stage 1: column dot-products, 4 partial accumulators to break FMA chain
    for (int a = t; a < D_DIM; a += 256) {
        float a0 = 0.f, a1 = 0.f, a2 = 0.f, a3 = 0.f;
        #pragma unroll 4
        for (int d = 0; d < D_DIM; d += 4) {
            a0 = fmaf(qs[d+0], Wq[(size_t)(d+0)*D_DIM + a], a0);
            a1 = fmaf(qs[d+1], Wq[(size_t)(d+1)*D_DIM + a], a1);
            a2 = fmaf(qs[d+2], Wq[(size_t)(d+2)*D_DIM + a], a2);
            a3 = fmaf(qs[d+3], Wq[(size_t)(d+3)*D_DIM + a], a3);
        }
        qv[a] = (a0 + a1) + (a2 + a3) + bq[a];
    }
    __syncthreads();
    // stage 2: row dot-products (coalesced float4 within row)
    for (int d = t; d < D_DIM; d += 256) {
        const float4* row = (const float4*)(Wk + (size_t)d*D_DIM);
        const float4* q4 = (const float4*)qv;
        float acc = 0.f;
        #pragma unroll 4
        for (int a4 = 0; a4 < D_DIM/4; ++a4) {
            float4 w = row[a4], q = q4[a4];
            acc = fmaf(w.x, q.x, acc); acc = fmaf(w.y, q.y, acc);
            acc = fmaf(w.z, q.z, acc); acc = fmaf(w.w, q.w, acc);
        }
        v_all[((size_t)b*2 + br)*D_DIM + d] = acc * INV_SCALE;
    }
    float part = 0.f;
    for (int a = t; a < D_DIM; a += 256) part = fmaf(qv[a], bk[a], part);
    red[t] = part; __syncthreads();
    for (int s = 128; s; s >>= 1) { if (t < s) red[t] += red[t + s]; __syncthreads(); }
    if (t == 0) c_all[b*2 + br] = red[0] * INV_SCALE + (br ? 0.f : r[0]);
}

// -------- kernel 2: energies, one pass over key, 2 rows in flight --------
__global__ __launch_bounds__(256) void energy_kernel(
    const float* __restrict__ key, const int* __restrict__ mask,
    const float* __restrict__ v_all, const float* __restrict__ c_all,
    float* __restrict__ e_mono, float* __restrict__ e_c)
{
    const int b = blockIdx.x;
    const int kb0 = blockIdx.y * 125;          // 16 chunks * 125 = 2000
    const int kend = kb0 + 125;
    const int lane = threadIdx.x & 63;
    const int wave = threadIdx.x >> 6;
    const float4* vm4 = (const float4*)(v_all + ((size_t)b*2 + 0)*D_DIM);
    const float4* vc4 = (const float4*)(v_all + ((size_t)b*2 + 1)*D_DIM);
    const float4 vmA = vm4[lane*2], vmB = vm4[lane*2 + 1];
    const float4 vcA = vc4[lane*2], vcB = vc4[lane*2 + 1];
    const float cm = c_all[b*2 + 0], cc = c_all[b*2 + 1];

    for (int k = kb0 + wave; k < kend; k += 8) {
        const int k2 = k + 4;
        const bool has2 = (k2 < kend);
        const float4* kr0 = (const float4*)(key + ((size_t)b*K_LEN + k)*D_DIM);
        const float4* kr1 = (const float4*)(key + ((size_t)b*K_LEN + (has2 ? k2 : k))*D_DIM);
        float4 a0 = kr0[lane*2], b0 = kr0[lane*2 + 1];
        float4 a1 = kr1[lane*2], b1 = kr1[lane*2 + 1];
        float dm0 = 0.f, dc0 = 0.f, dm1 = 0.f, dc1 = 0.f;
        dm0 = fmaf(a0.x, vmA.x, dm0); dm0 = fmaf(a0.y, vmA.y, dm0);
        dm0 = fmaf(a0.z, vmA.z, dm0); dm0 = fmaf(a0.w, vmA.w, dm0);
        dm0 = fmaf(b0.x, vmB.x, dm0); dm0 = fmaf(b0.y, vmB.y, dm0);
        dm0 = fmaf(b0.z, vmB.z, dm0); dm0 = fmaf(b0.w, vmB.w, dm0);
        dc0 = fmaf(a0.x, vcA.x, dc0); dc0 = fmaf(a0.y, vcA.y, dc0);
        dc0 = fmaf(a0.z, vcA.z, dc0); dc0 = fmaf(a0.w, vcA.w, dc0);
        dc0 = fmaf(b0.x, vcB.x, dc0); dc0 = fmaf(b0.y, vcB.y, dc0);
        dc0 = fmaf(b0.z, vcB.z, dc0); dc0 = fmaf(b0.w, vcB.w, dc0);
        dm1 = fmaf(a1.x, vmA.x, dm1); dm1 = fmaf(a1.y, vmA.y, dm1);
        dm1 = fmaf(a1.z, vmA.z, dm1); dm1 = fmaf(a1.w, vmA.w, dm1);
        dm1 = fmaf(b1.x, vmB.x, dm1); dm1 = fmaf(b1.y, vmB.y, dm1);
        dm1 = fmaf(b1.z, vmB.z, dm1); dm1 = fmaf(b1.w, vmB.w, dm1);
        dc1 = fmaf(a1.x, vcA.x, dc1); dc1 = fmaf(a1.y, vcA.y, dc1);
        dc1 = fmaf(a1.z, vcA.z, dc1); dc1 = fmaf(a1.w, vcA.w, dc1);
        dc1 = fmaf(b1.x, vcB.x, dc1); dc1 = fmaf(b1.y, vcB.y, dc1);
        dc1 = fmaf(b1.z, vcB.z, dc1); dc1 = fmaf(b1.w, vcB.w, dc1);
        #pragma unroll
        for (int off = 32; off; off >>= 1) {
            dm0 += __shfl_xor(dm0, off); dc0 += __shfl_xor(dc0, off);
            dm1 += __shfl_xor(dm1, off); dc1 += __shfl_xor(dc1, off);
        }
        if (lane == 0) {
            size_t gk = (size_t)b*K_LEN + k;
            bool mk = mask[gk] != 0;
            e_mono[gk] = mk ? dm0 + cm : NEG_INF;
            e_c[gk]    = mk ? dc0 + cc : NEG_INF;
            if (has2) {
                size_t gk2 = (size_t)b*K_LEN + k2;
                bool mk2 = mask[gk2] != 0;
                e_mono[gk2] = mk2 ? dm1 + cm : NEG_INF;
                e_c[gk2]    = mk2 ? dc1 + cc : NEG_INF;
            }
        }
    }
}

// -------- kernel 3: per-batch scans -> alpha, beta (wave-shuffle scans) ----
__global__ __launch_bounds__(256) void scan_kernel(
    const float* __restrict__ e_mono_g, const float* __restrict__ e_c_g,
    const float* __restrict__ noise, const float* __restrict__ aw_prev,
    float* __restrict__ alpha_out, float* __restrict__ beta_out)
{
    const int b = blockIdx.x, t = threadIdx.x;
    const int lane = t & 63, wv = t >> 6;
    __shared__ float sal[2048];  // alpha
    __shared__ float sse[2048];  // e_c then sm_exp
    __shared__ float su[2048];   // alpha/denom
    __shared__ float wsA[4], wsB[4], wsM[4];

    const float* em = e_mono_g + (size_t)b*K_LEN;
    const float* ec = e_c_g   + (size_t)b*K_LEN;
    const float* nz = noise   + (size_t)b*K_LEN;
    const float* aw = aw_prev + (size_t)b*K_LEN;

    const int base = t*8;
    float p[8], lg[8];
    #pragma unroll
    for (int j = 0; j < 8; ++j) {
        const int k = base + j;
        float pv = 0.f, lv = 0.f, ecv = NEG_INF;
        if (k < K_LEN) {
            float e = em[k] + nz[k];                 // NOISE_STD = 1
            pv = 1.f / (1.f + __expf(-e) * 1.0f);    // use precise expf below
            pv = 1.f / (1.f + expf(-e));
            float om = fminf(fmaxf(1.f - pv, EPS_C), 1.f);
            lv = logf(om);
            ecv = ec[k];
        }
        p[j] = pv; lg[j] = lv; sse[k] = ecv;
    }

    // ---- scan 1: exclusive cumsum of log(1-p) ----
    float ex[8]; float run = 0.f;
    #pragma unroll
    for (int j = 0; j < 8; ++j) { ex[j] = run; run += lg[j]; }
    float incl = run;
    #pragma unroll
    for (int off = 1; off < 64; off <<= 1) {
        float v = __shfl_up(incl, off, 64);
        if (lane >= off) incl += v;
    }
    if (lane == 63) wsA[wv] = incl;
    __syncthreads();                                         // (1)
    float wpre = 0.f;
    #pragma unroll
    for (int w = 0; w < 4; ++w) if (w < wv) wpre += wsA[w];
    const float pre = wpre + incl - run;                     // thread-exclusive

    // cp + scan 2 input
    float cp[8], t2i[8]; float run2 = 0.f;
    #pragma unroll
    for (int j = 0; j < 8; ++j) {
        const int k = base + j;
        float c = expf(pre + ex[j]);
        cp[j] = c;
        float t2 = 0.f;
        if (k < K_LEN) t2 = aw[k] / fminf(fmaxf(c, EPS_C), 1.f);
        run2 += t2; t2i[j] = run2;                           // thread-inclusive
    }
    float incl2 = run2;
    #pragma unroll
    for (int off = 1; off < 64; off <<= 1) {
        float v = __shfl_up(incl2, off, 64);
        if (lane >= off) incl2 += v;
    }
    if (lane == 63) wsB[wv] = incl2;
    __syncthreads();                                         // (2)
    float wpre2 = 0.f;
    #pragma unroll
    for (int w = 0; w < 4; ++w) if (w < wv) wpre2 += wsB[w];
    const float pre2 = wpre2 + incl2 - run2;
    #pragma unroll
    for (int j = 0; j < 8; ++j) {
        const int k = base + j;
        float al = p[j] * cp[j] * (pre2 + t2i[j]);
        sal[k] = al;
        if (k < K_LEN) alpha_out[(size_t)b*K_LEN + k] = al;
    }
    __syncthreads();                                         // (3) sse+sal done

    // ---- max over e_c ----
    float mx = NEG_INF;
    for (int k = t; k < 2048; k += 256) mx = fmaxf(mx, sse[k]);
    #pragma unroll
    for (int off = 32; off; off >>= 1) mx = fmaxf(mx, __shfl_xor(mx, off));
    if (lane == 0) wsM[wv] = mx;
    __syncthreads();                                         // (4)
    mx = fmaxf(fmaxf(wsM[0], wsM[1]), fmaxf(wsM[2], wsM[3]));

    for (int k = t; k < 2048; k += 256) {
        float se = 0.f;
        if (k < K_LEN) se = fmaxf(expf(sse[k] - mx), 1e-5f);
        sse[k] = se;
    }
    __syncthreads();                                         // (5)
    // denom = moving_sum(sm_exp, back=7, fwd=0); u = alpha/denom
    for (int k = t; k < 2048; k += 256) {
        float u = 0.f;
        if (k < K_LEN) {
            float den = 0.f;
            int j0 = (k > 7) ? (k - 7) : 0;
            for (int j = j0; j <= k; ++j) den += sse[j];
            u = sal[k] / den;                                // SHARP = 1
        }
        su[k] = u;
    }
    __syncthreads();                                         // (6)
    // beta = sm_exp * moving_sum(u, back=0, fwd=7)
    for (int k = t; k < K_LEN; k += 256) {
        float s2 = 0.f;
        #pragma unroll
        for (int j = 0; j < 8; ++j) s2 += su[k + j];
        beta_out[(size_t)b*K_LEN + k] = sse[k] * s2;
    }
}

// -------- kernel 4: cv partials, one pass over value --------
__global__ __launch_bounds__(256) void cv_part_kernel(
    const float* __restrict__ value, const float* __restrict__ beta,
    float* __restrict__ partial)   // [B][20][512]
{
    const int b = blockIdx.x, s = blockIdx.y, t = threadIdx.x;
    const int f4 = t & 127, half = t >> 7;
    const int k0 = s * 100;
    __shared__ float bs[100];
    __shared__ float4 comb[128];
    if (t < 100) bs[t] = beta[(size_t)b*K_LEN + k0 + t];
    __syncthreads();
    float4 acc = {0.f, 0.f, 0.f, 0.f};
    for (int k = k0 + half; k < k0 + 100; k += 2) {
        float4 vv = ((const float4*)(value + ((size_t)b*K_LEN + k)*D_DIM))[f4];
        float bb = bs[k - k0];
        acc.x = fmaf(bb, vv.x, acc.x); acc.y = fmaf(bb, vv.y, acc.y);
        acc.z = fmaf(bb, vv.z, acc.z); acc.w = fmaf(bb, vv.w, acc.w);
    }
    if (half) comb[f4] = acc;
    __syncthreads();
    if (!half) {
        float4 o = comb[f4];
        acc.x += o.x; acc.y += o.y; acc.z += o.z; acc.w += o.w;
        ((float4*)(partial + ((size_t)b*20 + s)*D_DIM))[f4] = acc;
    }
}

__global__ __launch_bounds__(256) void cv_reduce_kernel(
    const float* __restrict__ partial, float* __restrict__ cv)
{
    const int idx = blockIdx.x*256 + threadIdx.x;     // 0..32767
    const int b = idx >> 9, d = idx & 511;
    float acc = 0.f;
    #pragma unroll
    for (int s = 0; s < 20; ++s) acc += partial[((size_t)b*20 + s)*D_DIM + d];
    cv[idx] = acc;
}

extern "C" void kernel_launch(void* const* d_in, const int* in_sizes, int n_in,
                              void* d_out, int out_size, void* d_ws, size_t ws_size,
                              hipStream_t stream) {
    const float* key     = (const float*)d_in[0];
    const float* value   = (const float*)d_in[1];
    const float* query   = (const float*)d_in[2];
    const int*   mask    = (const int*)d_in[3];
    const float* aw_prev = (const float*)d_in[4];
    const float* noise   = (const float*)d_in[5];
    const float* Wk_m    = (const float*)d_in[6];
    const float* bk_m    = (const float*)d_in[7];
    const float* Wq_m    = (const float*)d_in[8];
    const float* bq_m    = (const float*)d_in[9];
    const float* r       = (const float*)d_in[10];
    const float* Wk_c    = (const float*)d_in[11];
    const float* bk_c    = (const float*)d_in[12];
    const float* Wq_c    = (const float*)d_in[13];
    const float* bq_c    = (const float*)d_in[14];

    float* out   = (float*)d_out;
    float* cv    = out;                       // [64,1,512] = 32768
    float* alpha = out + (size_t)B_N*D_DIM;   // [64,2000]  = 128000

    float* ws      = (float*)d_ws;
    float* e_mono  = ws;                  // 128000
    float* e_c     = ws + 128000;         // 128000
    float* beta    = ws + 256000;         // 128000
    float* v_all   = ws + 384000;         // 65536
    float* c_all   = ws + 449536;         // 128
    float* partial = ws + 449664;         // 64*20*512 = 655360

    proj_kernel<<<dim3(B_N, 2), 256, 0, stream>>>(query, Wq_m, bq_m, Wq_c, bq_c,
                                                  Wk_m, bk_m, Wk_c, bk_c, r,
                                                  v_all, c_all);
    energy_kernel<<<dim3(B_N, 16), 256, 0, stream>>>(key, mask, v_all, c_all, e_mono, e_c);
    scan_kernel<<<B_N, 256, 0, stream>>>(e_mono, e_c, noise, aw_prev, alpha, beta);
    cv_part_kernel<<<dim3(B_N, 20), 256, 0, stream>>>(value, beta, partial);
    cv_reduce_kernel<<<32768/256, 256, 0, stream>>>(partial, cv);
}